// Round 7
// baseline (239.813 us; speedup 1.0000x reference)
//
#include <hip/hip_runtime.h>

// GCN 2-layer + BatchNorm1d forward.
// R7: CSR front-end rebuilt for occupancy (R6: scatB at 128 blocks = 4.5%
//     occupancy, 62us of pure latency). New pipeline is atomic-free counting
//     sort: hist (per-block LDS hist -> ghist[block][1024], coalesced) ->
//     bscan2 (column prefix over blocks + bucket scan -> exact per-
//     (block,bucket) windows) -> scatB single scatter pass at 1024 thr/block.
//     Removes histA's redundant edge pass + all global cursor atomics.
//     buildC bumped to 512 threads.
// Kept: layer-1 commute A(XW)=(AX)W (both gathers on 64-dim fp16 rows, f32
//     accum), dot2 GEMMs, atomic-free BN.
// Pipeline: hist -> bscan2 -> scatB -> buildC (CSR+dis)
//   -> prescale es=fp16(dis*emb) -> agg64 ag1=fp16(dis*(es_i+Σes_src))
//   -> gemmA t1=fp16(ag1@W1+b1) -> gemmB hs2=fp16(dis*(t1@W2))
//   -> agg64 h2=fp16(dis*acc+b2) -> bn_part -> bn_final -> bn_apply -> f32.

#define EPS_BN 1e-5f
#define NBKT_PAD 1024   // >= ceil(N/128); N=100000 -> 782 buckets
#define BN_NB 128       // bn_part blocks (partial-sum slots)
#define SCAT_B 256      // edge-pass blocks (1024 threads each)

typedef _Float16 f16;
typedef _Float16 f16x2 __attribute__((ext_vector_type(2)));
union pk4 { ushort4 u; f16 h[4]; f16x2 h2[2]; };

#if __has_builtin(__builtin_amdgcn_fdot2)
__device__ __forceinline__ float fdot2(f16x2 a, f16x2 b, float c) {
    return __builtin_amdgcn_fdot2(a, b, c, false);
}
#else
__device__ __forceinline__ float fdot2(f16x2 a, f16x2 b, float c) {
    return c + (float)a[0] * (float)b[0] + (float)a[1] * (float)b[1];
}
#endif

// ---------------- hist: per-block bucket histogram -> ghist (no atomics to HBM) ----------------
__global__ __launch_bounds__(1024) void hist_k(const int* __restrict__ colv, int E, int epb,
                                               int* __restrict__ ghist) {
    __shared__ int bins[NBKT_PAD];
    int tid = threadIdx.x;
    bins[tid] = 0;
    __syncthreads();
    int e0 = blockIdx.x * epb;
    int e1 = min(E, e0 + epb);
    for (int e = e0 + tid; e < e1; e += 1024)
        atomicAdd(&bins[colv[e] >> 7], 1);
    __syncthreads();
    ghist[blockIdx.x * NBKT_PAD + tid] = bins[tid];
}

// ---------------- bscan2: per-bucket prefix over blocks + bucket scan ----------------
// After this: ghist[b][k] = global write offset for block b's run into bucket k;
// bstart[k] = bucket k start; bstart[1024] = E; start[n] = E.
__global__ __launch_bounds__(1024) void bscan2_k(int* __restrict__ ghist,
                                                 int* __restrict__ bstart,
                                                 int* __restrict__ start, int n, int E) {
    __shared__ int s[1024];
    int tid = threadIdx.x;
    int run = 0;
    for (int b = 0; b < SCAT_B; b++) {           // coalesced: row b, all 1024 lanes
        int t = ghist[b * NBKT_PAD + tid];
        ghist[b * NBKT_PAD + tid] = run;         // prefix within bucket
        run += t;
    }
    int total = run;
    s[tid] = total; __syncthreads();
    for (int off = 1; off < 1024; off <<= 1) {
        int t = (tid >= off) ? s[tid - off] : 0;
        __syncthreads();
        s[tid] += t;
        __syncthreads();
    }
    int excl = s[tid] - total;
    bstart[tid] = excl;
    if (tid == 1023) bstart[1024] = s[1023];
    if (tid == 0) start[n] = E;
    for (int b = 0; b < SCAT_B; b++)
        ghist[b * NBKT_PAD + tid] += excl;       // absolute window start
}

// ---------------- scatB: single-pass scatter of packed edges into buckets ----------------
__global__ __launch_bounds__(1024) void scatB_k(const int* __restrict__ rowv, const int* __restrict__ colv,
                                                int E, int epb, const int* __restrict__ ghist,
                                                unsigned* __restrict__ ebuf) {
    __shared__ int bins[NBKT_PAD];
    int tid = threadIdx.x;
    bins[tid] = ghist[blockIdx.x * NBKT_PAD + tid];   // write cursors
    __syncthreads();
    int e0 = blockIdx.x * epb;
    int e1 = min(E, e0 + epb);
    for (int e = e0 + tid; e < e1; e += 1024) {
        int c = colv[e];
        int p = atomicAdd(&bins[c >> 7], 1);
        ebuf[p] = ((unsigned)rowv[e] << 7) | (unsigned)(c & 127);
    }
}

// ---------------- buildC: per-bucket CSR finalize ----------------
__global__ __launch_bounds__(512) void buildC_k(const unsigned* __restrict__ ebuf,
                                                const int* __restrict__ bstart,
                                                int* __restrict__ start, int* __restrict__ srcs,
                                                float* __restrict__ dis, int n) {
    __shared__ int ncnt[128], noff[128], stmp[128];
    int b = blockIdx.x;
    int tid = threadIdx.x;
    int e0 = bstart[b], e1 = bstart[b + 1];
    if (tid < 128) ncnt[tid] = 0;
    __syncthreads();
    for (int e = e0 + tid; e < e1; e += 512)
        atomicAdd(&ncnt[ebuf[e] & 127u], 1);
    __syncthreads();
    if (tid < 128) stmp[tid] = ncnt[tid];
    __syncthreads();
    for (int off = 1; off < 128; off <<= 1) {
        int t = (tid < 128 && tid >= off) ? stmp[tid - off] : 0;
        __syncthreads();
        if (tid < 128) stmp[tid] += t;
        __syncthreads();
    }
    if (tid < 128) {
        int excl = stmp[tid] - ncnt[tid];
        noff[tid] = e0 + excl;
        int node = b * 128 + tid;
        if (node < n) {
            start[node] = e0 + excl;
            dis[node] = rsqrtf((float)(ncnt[tid] + 1));   // +1 self-loop
        }
    }
    __syncthreads();
    for (int e = e0 + tid; e < e1; e += 512) {
        unsigned p = ebuf[e];
        int pos = atomicAdd(&noff[p & 127u], 1);
        srcs[pos] = (int)(p >> 7);
    }
}

// ---------------- prescale: es = fp16(dis * emb), 64-dim ----------------
__global__ __launch_bounds__(256) void prescale_k(const float* __restrict__ emb,
                                                  const float* __restrict__ dis,
                                                  f16* __restrict__ es, int n) {
    int gid = blockIdx.x * 256 + threadIdx.x;
    int node = gid >> 4, q = gid & 15;
    if (node >= n) return;
    float d = dis[node];
    float4 v = ((const float4*)emb)[(size_t)node * 16 + q];
    pk4 p;
    p.h[0] = (f16)(v.x * d); p.h[1] = (f16)(v.y * d);
    p.h[2] = (f16)(v.z * d); p.h[3] = (f16)(v.w * d);
    ((ushort4*)es)[(size_t)node * 16 + q] = p.u;
}

__device__ __forceinline__ void acc_pk(float4& acc, ushort4 u) {
    pk4 p; p.u = u;
    acc.x += (float)p.h[0]; acc.y += (float)p.h[1];
    acc.z += (float)p.h[2]; acc.w += (float)p.h[3];
}

// ---------------- agg over 64-dim fp16 table: 16 lanes/node ----------------
__global__ __launch_bounds__(256) void agg64_k(const f16* __restrict__ table, const int* __restrict__ start,
                                               const int* __restrict__ srcs, const float* __restrict__ dis,
                                               const float* __restrict__ bias, f16* __restrict__ out, int n) {
    int node = blockIdx.x * 16 + (threadIdx.x >> 4);
    if (node >= n) return;
    int lane = threadIdx.x & 15;
    const ushort4* t4 = (const ushort4*)table;
    float4 acc = make_float4(0.f, 0.f, 0.f, 0.f);
    acc_pk(acc, t4[(size_t)node * 16 + lane]);            // self-loop term
    int s0 = start[node], s1 = start[node + 1];
    int e = s0;
    for (; e + 7 < s1; e += 8) {
        int i0 = srcs[e],     i1 = srcs[e + 1], i2 = srcs[e + 2], i3 = srcs[e + 3];
        int i4 = srcs[e + 4], i5 = srcs[e + 5], i6 = srcs[e + 6], i7 = srcs[e + 7];
        ushort4 v0 = t4[(size_t)i0 * 16 + lane];
        ushort4 v1 = t4[(size_t)i1 * 16 + lane];
        ushort4 v2 = t4[(size_t)i2 * 16 + lane];
        ushort4 v3 = t4[(size_t)i3 * 16 + lane];
        ushort4 v4 = t4[(size_t)i4 * 16 + lane];
        ushort4 v5 = t4[(size_t)i5 * 16 + lane];
        ushort4 v6 = t4[(size_t)i6 * 16 + lane];
        ushort4 v7 = t4[(size_t)i7 * 16 + lane];
        acc_pk(acc, v0); acc_pk(acc, v1); acc_pk(acc, v2); acc_pk(acc, v3);
        acc_pk(acc, v4); acc_pk(acc, v5); acc_pk(acc, v6); acc_pk(acc, v7);
    }
    for (; e + 3 < s1; e += 4) {
        int i0 = srcs[e], i1 = srcs[e + 1], i2 = srcs[e + 2], i3 = srcs[e + 3];
        ushort4 v0 = t4[(size_t)i0 * 16 + lane];
        ushort4 v1 = t4[(size_t)i1 * 16 + lane];
        ushort4 v2 = t4[(size_t)i2 * 16 + lane];
        ushort4 v3 = t4[(size_t)i3 * 16 + lane];
        acc_pk(acc, v0); acc_pk(acc, v1); acc_pk(acc, v2); acc_pk(acc, v3);
    }
    for (; e < s1; e++) acc_pk(acc, t4[(size_t)srcs[e] * 16 + lane]);
    float d = dis[node];
    float4 b = make_float4(0.f, 0.f, 0.f, 0.f);
    if (bias) b = ((const float4*)bias)[lane];
    pk4 p;
    p.h[0] = (f16)(acc.x * d + b.x); p.h[1] = (f16)(acc.y * d + b.y);
    p.h[2] = (f16)(acc.z * d + b.z); p.h[3] = (f16)(acc.w * d + b.w);
    ((ushort4*)out)[(size_t)node * 16 + lane] = p.u;
}

// ---------------- gemmA: t1 = fp16(ag1[n,64] @ W1[64,128] + b1) ----------------
__global__ __launch_bounds__(256) void gemmA_k(const f16* __restrict__ ag1, const float* __restrict__ W1,
                                               const float* __restrict__ b1, f16* __restrict__ t1, int n) {
    __shared__ f16x2 sW[32 * 128];    // [kk][c] = (W1[2kk][c], W1[2kk+1][c])
    __shared__ f16x2 sA[32 * 34];     // [r][kk], padded
    int tid = threadIdx.x;
    for (int i = tid; i < 32 * 128; i += 256) {
        int kk = i >> 7, c = i & 127;
        f16x2 w; w[0] = (f16)W1[(2 * kk) * 128 + c]; w[1] = (f16)W1[(2 * kk + 1) * 128 + c];
        sW[i] = w;
    }
    int rowbase = blockIdx.x * 32;
    for (int i = tid; i < 512; i += 256) {            // 32 rows x 16 ushort4
        int r = i >> 4, q = i & 15;
        int gr = rowbase + r;
        ushort4 u = make_ushort4(0, 0, 0, 0);
        if (gr < n) u = ((const ushort4*)ag1)[(size_t)gr * 16 + q];
        ((ushort4*)sA)[r * 17 + q] = u;
    }
    __syncthreads();
    int L = tid & 31, rg = tid >> 5;                  // cols 4L..4L+3, rows rg*4..+3
    float acc[4][4] = {};
#pragma unroll 4
    for (int kk = 0; kk < 32; kk++) {
        f16x2 w0 = sW[kk * 128 + 4 * L];
        f16x2 w1 = sW[kk * 128 + 4 * L + 1];
        f16x2 w2 = sW[kk * 128 + 4 * L + 2];
        f16x2 w3 = sW[kk * 128 + 4 * L + 3];
#pragma unroll
        for (int rr = 0; rr < 4; rr++) {
            f16x2 a = sA[(rg * 4 + rr) * 34 + kk];
            acc[rr][0] = fdot2(a, w0, acc[rr][0]);
            acc[rr][1] = fdot2(a, w1, acc[rr][1]);
            acc[rr][2] = fdot2(a, w2, acc[rr][2]);
            acc[rr][3] = fdot2(a, w3, acc[rr][3]);
        }
    }
    float4 bb = *(const float4*)(b1 + 4 * L);
#pragma unroll
    for (int rr = 0; rr < 4; rr++) {
        int row = rowbase + rg * 4 + rr;
        if (row < n) {
            pk4 p;
            p.h[0] = (f16)(acc[rr][0] + bb.x); p.h[1] = (f16)(acc[rr][1] + bb.y);
            p.h[2] = (f16)(acc[rr][2] + bb.z); p.h[3] = (f16)(acc[rr][3] + bb.w);
            ((ushort4*)t1)[(size_t)row * 32 + L] = p.u;
        }
    }
}

// ---------------- gemmB: hs2 = fp16(dis * (t1[n,128] @ W2[128,64])) ----------------
__global__ __launch_bounds__(256) void gemmB_k(const f16* __restrict__ t1, const float* __restrict__ W2,
                                               const float* __restrict__ dis, f16* __restrict__ hs2, int n) {
    __shared__ f16x2 sW[64 * 64];     // [kk][c] = (W2[2kk][c], W2[2kk+1][c])
    __shared__ f16x2 sA[64 * 66];     // [r][kk], padded (+2)
    int tid = threadIdx.x;
    for (int i = tid; i < 64 * 64; i += 256) {
        int kk = i >> 6, c = i & 63;
        f16x2 w; w[0] = (f16)W2[(2 * kk) * 64 + c]; w[1] = (f16)W2[(2 * kk + 1) * 64 + c];
        sW[i] = w;
    }
    int rowbase = blockIdx.x * 64;
    for (int i = tid; i < 2048; i += 256) {           // 64 rows x 32 ushort4
        int r = i >> 5, q = i & 31;
        int gr = rowbase + r;
        ushort4 u = make_ushort4(0, 0, 0, 0);
        if (gr < n) u = ((const ushort4*)t1)[(size_t)gr * 32 + q];
        ((ushort4*)sA)[r * 33 + q] = u;
    }
    __syncthreads();
    int L = tid & 15, rg = tid >> 4;                  // cols 4L..4L+3, rows rg*4..+3
    float acc[4][4] = {};
#pragma unroll 4
    for (int kk = 0; kk < 64; kk++) {
        f16x2 w0 = sW[kk * 64 + 4 * L];
        f16x2 w1 = sW[kk * 64 + 4 * L + 1];
        f16x2 w2 = sW[kk * 64 + 4 * L + 2];
        f16x2 w3 = sW[kk * 64 + 4 * L + 3];
#pragma unroll
        for (int rr = 0; rr < 4; rr++) {
            f16x2 a = sA[(rg * 4 + rr) * 66 + kk];
            acc[rr][0] = fdot2(a, w0, acc[rr][0]);
            acc[rr][1] = fdot2(a, w1, acc[rr][1]);
            acc[rr][2] = fdot2(a, w2, acc[rr][2]);
            acc[rr][3] = fdot2(a, w3, acc[rr][3]);
        }
    }
#pragma unroll
    for (int rr = 0; rr < 4; rr++) {
        int row = rowbase + rg * 4 + rr;
        if (row < n) {
            float d = dis[row];
            pk4 p;
            p.h[0] = (f16)(acc[rr][0] * d); p.h[1] = (f16)(acc[rr][1] * d);
            p.h[2] = (f16)(acc[rr][2] * d); p.h[3] = (f16)(acc[rr][3] * d);
            ((ushort4*)hs2)[(size_t)row * 16 + L] = p.u;
        }
    }
}

// ---------------- batchnorm: per-block partials, NO global atomics ----------------
__global__ __launch_bounds__(256) void bn_part_k(const f16* __restrict__ x, float* __restrict__ pbuf, int n) {
    __shared__ float4 ls[256], lq[256];
    int q = threadIdx.x & 15;     // cols 4q..4q+3
    int rg = threadIdx.x >> 4;    // 0..15
    float4 s = make_float4(0.f, 0.f, 0.f, 0.f);
    float4 ss = make_float4(0.f, 0.f, 0.f, 0.f);
    for (int row = blockIdx.x * 16 + rg; row < n; row += gridDim.x * 16) {
        pk4 p; p.u = ((const ushort4*)x)[(size_t)row * 16 + q];
        float v0 = p.h[0], v1 = p.h[1], v2 = p.h[2], v3 = p.h[3];
        s.x += v0; s.y += v1; s.z += v2; s.w += v3;
        ss.x += v0 * v0; ss.y += v1 * v1; ss.z += v2 * v2; ss.w += v3 * v3;
    }
    ls[threadIdx.x] = s; lq[threadIdx.x] = ss;
    __syncthreads();
    if (threadIdx.x < 16) {
        float4 S = make_float4(0.f, 0.f, 0.f, 0.f);
        float4 Q = make_float4(0.f, 0.f, 0.f, 0.f);
        for (int g = 0; g < 16; g++) {
            float4 a = ls[g * 16 + threadIdx.x], b = lq[g * 16 + threadIdx.x];
            S.x += a.x; S.y += a.y; S.z += a.z; S.w += a.w;
            Q.x += b.x; Q.y += b.y; Q.z += b.z; Q.w += b.w;
        }
        float4* dst = (float4*)(pbuf + (size_t)blockIdx.x * 128);
        dst[threadIdx.x] = S;
        dst[threadIdx.x + 16] = Q;
    }
}

__global__ __launch_bounds__(64) void bn_final_k(const float* __restrict__ pbuf,
                                                 const float* __restrict__ gamma, const float* __restrict__ beta,
                                                 int n, float* __restrict__ scale, float* __restrict__ shift) {
    int c = threadIdx.x;
    float s = 0.f, q = 0.f;
    for (int b = 0; b < BN_NB; b++) {
        s += pbuf[b * 128 + c];
        q += pbuf[b * 128 + 64 + c];
    }
    float inv_n = 1.f / (float)n;
    float mean = s * inv_n;
    float var = q * inv_n - mean * mean;          // biased variance
    float sc = gamma[c] * rsqrtf(var + EPS_BN);
    scale[c] = sc;
    shift[c] = beta[c] - mean * sc;
}

__global__ __launch_bounds__(256) void bn_apply_k(const f16* __restrict__ x, const float* __restrict__ scale,
                                                  const float* __restrict__ shift, float* __restrict__ out, int n) {
    __shared__ float sscale[64], sshift[64];
    if (threadIdx.x < 64) {
        sscale[threadIdx.x] = scale[threadIdx.x];
        sshift[threadIdx.x] = shift[threadIdx.x];
    }
    __syncthreads();
    int i = blockIdx.x * 256 + threadIdx.x;
    if (i < n * 16) {
        int c = (i & 15) * 4;
        pk4 p; p.u = ((const ushort4*)x)[i];
        float4 o;
        o.x = (float)p.h[0] * sscale[c]     + sshift[c];
        o.y = (float)p.h[1] * sscale[c + 1] + sshift[c + 1];
        o.z = (float)p.h[2] * sscale[c + 2] + sshift[c + 2];
        o.w = (float)p.h[3] * sscale[c + 3] + sshift[c + 3];
        ((float4*)out)[i] = o;
    }
}

extern "C" void kernel_launch(void* const* d_in, const int* in_sizes, int n_in,
                              void* d_out, int out_size, void* d_ws, size_t ws_size,
                              hipStream_t stream) {
    const float* emb   = (const float*)d_in[0];
    const float* W1    = (const float*)d_in[1];
    const float* b1    = (const float*)d_in[2];
    const float* W2    = (const float*)d_in[3];
    const float* b2    = (const float*)d_in[4];
    const float* gamma = (const float*)d_in[5];
    const float* beta  = (const float*)d_in[6];
    const int*   ei    = (const int*)d_in[7];     // [2,E] int32
    const int n = in_sizes[0] / 64;               // 100000
    const int E = in_sizes[7] / 2;                // 1600000
    const int* rowv = ei;                         // sources
    const int* colv = ei + E;                     // targets
    const int NBKT = (n + 127) / 128;             // 782

    char* ws = (char*)d_ws;
    size_t o = 0;
    auto alloc = [&](size_t bytes) -> char* {
        char* p = ws + o;
        o = (o + bytes + 255) & ~(size_t)255;
        return p;
    };
    int*   ghist   = (int*)alloc((size_t)SCAT_B * NBKT_PAD * 4);  // 1MB
    int*   bstart  = (int*)alloc((NBKT_PAD + 1) * 4);
    int*   start   = (int*)alloc((size_t)(n + 1) * 4);
    float* dis     = (float*)alloc((size_t)n * 4);
    int*   srcs    = (int*)alloc((size_t)E * 4);
    float* pbuf    = (float*)alloc(BN_NB * 128 * 4);     // BN partials
    float* bnscale = (float*)alloc(256);
    float* bnshift = (float*)alloc(256);
    f16*   es      = (f16*)alloc((size_t)n * 64 * 2);    // dis*emb fp16
    f16*   ag1     = (f16*)alloc((size_t)n * 64 * 2);    // layer-1 aggregated
    f16*   t1      = (f16*)alloc((size_t)n * 128 * 2);   // h1 = ag1@W1+b1
    f16*   hs2     = (f16*)alloc((size_t)n * 64 * 2);    // dis*(t1@W2)
    f16*   h2      = (f16*)alloc((size_t)n * 64 * 2);    // pre-BN output
    unsigned* ebuf = (unsigned*)alloc((size_t)E * 4);    // packed bucket edges

    int epb = (E + SCAT_B - 1) / SCAT_B;          // 6250

    hist_k<<<SCAT_B, 1024, 0, stream>>>(colv, E, epb, ghist);
    bscan2_k<<<1, 1024, 0, stream>>>(ghist, bstart, start, n, E);
    scatB_k<<<SCAT_B, 1024, 0, stream>>>(rowv, colv, E, epb, ghist, ebuf);
    buildC_k<<<NBKT, 512, 0, stream>>>(ebuf, bstart, start, srcs, dis, n);

    prescale_k<<<(n * 16 + 255) / 256, 256, 0, stream>>>(emb, dis, es, n);
    agg64_k<<<(n + 15) / 16, 256, 0, stream>>>(es, start, srcs, dis, nullptr, ag1, n);
    gemmA_k<<<(n + 31) / 32, 256, 0, stream>>>(ag1, W1, b1, t1, n);
    gemmB_k<<<(n + 63) / 64, 256, 0, stream>>>(t1, W2, dis, hs2, n);
    agg64_k<<<(n + 15) / 16, 256, 0, stream>>>(hs2, start, srcs, dis, b2, h2, n);

    bn_part_k<<<BN_NB, 256, 0, stream>>>(h2, pbuf, n);
    bn_final_k<<<1, 64, 0, stream>>>(pbuf, gamma, beta, n, bnscale, bnshift);
    bn_apply_k<<<(n * 16 + 255) / 256, 256, 0, stream>>>(h2, bnscale, bnshift, (float*)d_out, n);
}

// Round 8
// 199.931 us; speedup vs baseline: 1.1995x; 1.1995x over previous
//
#include <hip/hip_runtime.h>

// GCN 2-layer + BatchNorm1d forward.
// R8: parallelize the CSR scan (R7: bscan2_k = 1 block doing 512 serial global
//     round-trips = 51.8us at 0.16% occupancy). Now: scan_bucket (1024 blocks,
//     one per bucket, LDS scan over 256 block-counts) -> scan_total (1024-wide
//     bucket scan) ; the +bstart add-back is folded into scatB's cursor init.
// Kept: layer-1 commute A(XW)=(AX)W (both gathers on 64-dim fp16 rows, f32
//     accum), counting-sort CSR build at 1024thr/block, dot2 GEMMs,
//     atomic-free BN.
// Pipeline: hist -> scan_bucket -> scan_total -> scatB -> buildC (CSR+dis)
//   -> prescale es=fp16(dis*emb) -> agg64 ag1=fp16(dis*(es_i+Σes_src))
//   -> gemmA t1=fp16(ag1@W1+b1) -> gemmB hs2=fp16(dis*(t1@W2))
//   -> agg64 h2=fp16(dis*acc+b2) -> bn_part -> bn_final -> bn_apply -> f32.

#define EPS_BN 1e-5f
#define NBKT_PAD 1024   // >= ceil(N/128); N=100000 -> 782 buckets
#define BN_NB 128       // bn_part blocks (partial-sum slots)
#define SCAT_B 256      // edge-pass blocks (1024 threads each)

typedef _Float16 f16;
typedef _Float16 f16x2 __attribute__((ext_vector_type(2)));
union pk4 { ushort4 u; f16 h[4]; f16x2 h2[2]; };

#if __has_builtin(__builtin_amdgcn_fdot2)
__device__ __forceinline__ float fdot2(f16x2 a, f16x2 b, float c) {
    return __builtin_amdgcn_fdot2(a, b, c, false);
}
#else
__device__ __forceinline__ float fdot2(f16x2 a, f16x2 b, float c) {
    return c + (float)a[0] * (float)b[0] + (float)a[1] * (float)b[1];
}
#endif

// ---------------- hist: per-block bucket histogram -> ghist ----------------
__global__ __launch_bounds__(1024) void hist_k(const int* __restrict__ colv, int E, int epb,
                                               int* __restrict__ ghist) {
    __shared__ int bins[NBKT_PAD];
    int tid = threadIdx.x;
    bins[tid] = 0;
    __syncthreads();
    int e0 = blockIdx.x * epb;
    int e1 = min(E, e0 + epb);
    for (int e = e0 + tid; e < e1; e += 1024)
        atomicAdd(&bins[colv[e] >> 7], 1);
    __syncthreads();
    ghist[blockIdx.x * NBKT_PAD + tid] = bins[tid];
}

// ---------------- scan_bucket: per-bucket exclusive prefix over the 256 blocks ----------------
// One block per bucket k: ghist[b][k] <- sum_{b'<b} ghist[b'][k];  bcnt[k] = bucket total.
__global__ __launch_bounds__(256) void scan_bucket_k(int* __restrict__ ghist, int* __restrict__ bcnt) {
    __shared__ int s[256];
    int k = blockIdx.x;
    int b = threadIdx.x;
    int v = ghist[b * NBKT_PAD + k];
    s[b] = v; __syncthreads();
    for (int off = 1; off < 256; off <<= 1) {
        int t = (b >= off) ? s[b - off] : 0;
        __syncthreads();
        s[b] += t;
        __syncthreads();
    }
    ghist[b * NBKT_PAD + k] = s[b] - v;           // exclusive within bucket
    if (b == 255) bcnt[k] = s[255];
}

// ---------------- scan_total: exclusive scan of bucket totals ----------------
__global__ __launch_bounds__(1024) void scan_total_k(const int* __restrict__ bcnt,
                                                     int* __restrict__ bstart,
                                                     int* __restrict__ start, int n, int E) {
    __shared__ int s[1024];
    int tid = threadIdx.x;
    int v = bcnt[tid];
    s[tid] = v; __syncthreads();
    for (int off = 1; off < 1024; off <<= 1) {
        int t = (tid >= off) ? s[tid - off] : 0;
        __syncthreads();
        s[tid] += t;
        __syncthreads();
    }
    bstart[tid] = s[tid] - v;
    if (tid == 1023) bstart[1024] = s[1023];
    if (tid == 0) start[n] = E;
}

// ---------------- scatB: single-pass scatter (cursor = ghist + bstart) ----------------
__global__ __launch_bounds__(1024) void scatB_k(const int* __restrict__ rowv, const int* __restrict__ colv,
                                                int E, int epb, const int* __restrict__ ghist,
                                                const int* __restrict__ bstart,
                                                unsigned* __restrict__ ebuf) {
    __shared__ int bins[NBKT_PAD];
    int tid = threadIdx.x;
    bins[tid] = ghist[blockIdx.x * NBKT_PAD + tid] + bstart[tid];
    __syncthreads();
    int e0 = blockIdx.x * epb;
    int e1 = min(E, e0 + epb);
    for (int e = e0 + tid; e < e1; e += 1024) {
        int c = colv[e];
        int p = atomicAdd(&bins[c >> 7], 1);
        ebuf[p] = ((unsigned)rowv[e] << 7) | (unsigned)(c & 127);
    }
}

// ---------------- buildC: per-bucket CSR finalize ----------------
__global__ __launch_bounds__(512) void buildC_k(const unsigned* __restrict__ ebuf,
                                                const int* __restrict__ bstart,
                                                int* __restrict__ start, int* __restrict__ srcs,
                                                float* __restrict__ dis, int n) {
    __shared__ int ncnt[128], noff[128], stmp[128];
    int b = blockIdx.x;
    int tid = threadIdx.x;
    int e0 = bstart[b], e1 = bstart[b + 1];
    if (tid < 128) ncnt[tid] = 0;
    __syncthreads();
    for (int e = e0 + tid; e < e1; e += 512)
        atomicAdd(&ncnt[ebuf[e] & 127u], 1);
    __syncthreads();
    if (tid < 128) stmp[tid] = ncnt[tid];
    __syncthreads();
    for (int off = 1; off < 128; off <<= 1) {
        int t = (tid < 128 && tid >= off) ? stmp[tid - off] : 0;
        __syncthreads();
        if (tid < 128) stmp[tid] += t;
        __syncthreads();
    }
    if (tid < 128) {
        int excl = stmp[tid] - ncnt[tid];
        noff[tid] = e0 + excl;
        int node = b * 128 + tid;
        if (node < n) {
            start[node] = e0 + excl;
            dis[node] = rsqrtf((float)(ncnt[tid] + 1));   // +1 self-loop
        }
    }
    __syncthreads();
    for (int e = e0 + tid; e < e1; e += 512) {
        unsigned p = ebuf[e];
        int pos = atomicAdd(&noff[p & 127u], 1);
        srcs[pos] = (int)(p >> 7);
    }
}

// ---------------- prescale: es = fp16(dis * emb), 64-dim ----------------
__global__ __launch_bounds__(256) void prescale_k(const float* __restrict__ emb,
                                                  const float* __restrict__ dis,
                                                  f16* __restrict__ es, int n) {
    int gid = blockIdx.x * 256 + threadIdx.x;
    int node = gid >> 4, q = gid & 15;
    if (node >= n) return;
    float d = dis[node];
    float4 v = ((const float4*)emb)[(size_t)node * 16 + q];
    pk4 p;
    p.h[0] = (f16)(v.x * d); p.h[1] = (f16)(v.y * d);
    p.h[2] = (f16)(v.z * d); p.h[3] = (f16)(v.w * d);
    ((ushort4*)es)[(size_t)node * 16 + q] = p.u;
}

__device__ __forceinline__ void acc_pk(float4& acc, ushort4 u) {
    pk4 p; p.u = u;
    acc.x += (float)p.h[0]; acc.y += (float)p.h[1];
    acc.z += (float)p.h[2]; acc.w += (float)p.h[3];
}

// ---------------- agg over 64-dim fp16 table: 16 lanes/node ----------------
__global__ __launch_bounds__(256) void agg64_k(const f16* __restrict__ table, const int* __restrict__ start,
                                               const int* __restrict__ srcs, const float* __restrict__ dis,
                                               const float* __restrict__ bias, f16* __restrict__ out, int n) {
    int node = blockIdx.x * 16 + (threadIdx.x >> 4);
    if (node >= n) return;
    int lane = threadIdx.x & 15;
    const ushort4* t4 = (const ushort4*)table;
    float4 acc = make_float4(0.f, 0.f, 0.f, 0.f);
    acc_pk(acc, t4[(size_t)node * 16 + lane]);            // self-loop term
    int s0 = start[node], s1 = start[node + 1];
    int e = s0;
    for (; e + 7 < s1; e += 8) {
        int i0 = srcs[e],     i1 = srcs[e + 1], i2 = srcs[e + 2], i3 = srcs[e + 3];
        int i4 = srcs[e + 4], i5 = srcs[e + 5], i6 = srcs[e + 6], i7 = srcs[e + 7];
        ushort4 v0 = t4[(size_t)i0 * 16 + lane];
        ushort4 v1 = t4[(size_t)i1 * 16 + lane];
        ushort4 v2 = t4[(size_t)i2 * 16 + lane];
        ushort4 v3 = t4[(size_t)i3 * 16 + lane];
        ushort4 v4 = t4[(size_t)i4 * 16 + lane];
        ushort4 v5 = t4[(size_t)i5 * 16 + lane];
        ushort4 v6 = t4[(size_t)i6 * 16 + lane];
        ushort4 v7 = t4[(size_t)i7 * 16 + lane];
        acc_pk(acc, v0); acc_pk(acc, v1); acc_pk(acc, v2); acc_pk(acc, v3);
        acc_pk(acc, v4); acc_pk(acc, v5); acc_pk(acc, v6); acc_pk(acc, v7);
    }
    for (; e + 3 < s1; e += 4) {
        int i0 = srcs[e], i1 = srcs[e + 1], i2 = srcs[e + 2], i3 = srcs[e + 3];
        ushort4 v0 = t4[(size_t)i0 * 16 + lane];
        ushort4 v1 = t4[(size_t)i1 * 16 + lane];
        ushort4 v2 = t4[(size_t)i2 * 16 + lane];
        ushort4 v3 = t4[(size_t)i3 * 16 + lane];
        acc_pk(acc, v0); acc_pk(acc, v1); acc_pk(acc, v2); acc_pk(acc, v3);
    }
    for (; e < s1; e++) acc_pk(acc, t4[(size_t)srcs[e] * 16 + lane]);
    float d = dis[node];
    float4 b = make_float4(0.f, 0.f, 0.f, 0.f);
    if (bias) b = ((const float4*)bias)[lane];
    pk4 p;
    p.h[0] = (f16)(acc.x * d + b.x); p.h[1] = (f16)(acc.y * d + b.y);
    p.h[2] = (f16)(acc.z * d + b.z); p.h[3] = (f16)(acc.w * d + b.w);
    ((ushort4*)out)[(size_t)node * 16 + lane] = p.u;
}

// ---------------- gemmA: t1 = fp16(ag1[n,64] @ W1[64,128] + b1) ----------------
__global__ __launch_bounds__(256) void gemmA_k(const f16* __restrict__ ag1, const float* __restrict__ W1,
                                               const float* __restrict__ b1, f16* __restrict__ t1, int n) {
    __shared__ f16x2 sW[32 * 128];    // [kk][c] = (W1[2kk][c], W1[2kk+1][c])
    __shared__ f16x2 sA[32 * 34];     // [r][kk], padded
    int tid = threadIdx.x;
    for (int i = tid; i < 32 * 128; i += 256) {
        int kk = i >> 7, c = i & 127;
        f16x2 w; w[0] = (f16)W1[(2 * kk) * 128 + c]; w[1] = (f16)W1[(2 * kk + 1) * 128 + c];
        sW[i] = w;
    }
    int rowbase = blockIdx.x * 32;
    for (int i = tid; i < 512; i += 256) {            // 32 rows x 16 ushort4
        int r = i >> 4, q = i & 15;
        int gr = rowbase + r;
        ushort4 u = make_ushort4(0, 0, 0, 0);
        if (gr < n) u = ((const ushort4*)ag1)[(size_t)gr * 16 + q];
        ((ushort4*)sA)[r * 17 + q] = u;
    }
    __syncthreads();
    int L = tid & 31, rg = tid >> 5;                  // cols 4L..4L+3, rows rg*4..+3
    float acc[4][4] = {};
#pragma unroll 4
    for (int kk = 0; kk < 32; kk++) {
        f16x2 w0 = sW[kk * 128 + 4 * L];
        f16x2 w1 = sW[kk * 128 + 4 * L + 1];
        f16x2 w2 = sW[kk * 128 + 4 * L + 2];
        f16x2 w3 = sW[kk * 128 + 4 * L + 3];
#pragma unroll
        for (int rr = 0; rr < 4; rr++) {
            f16x2 a = sA[(rg * 4 + rr) * 34 + kk];
            acc[rr][0] = fdot2(a, w0, acc[rr][0]);
            acc[rr][1] = fdot2(a, w1, acc[rr][1]);
            acc[rr][2] = fdot2(a, w2, acc[rr][2]);
            acc[rr][3] = fdot2(a, w3, acc[rr][3]);
        }
    }
    float4 bb = *(const float4*)(b1 + 4 * L);
#pragma unroll
    for (int rr = 0; rr < 4; rr++) {
        int row = rowbase + rg * 4 + rr;
        if (row < n) {
            pk4 p;
            p.h[0] = (f16)(acc[rr][0] + bb.x); p.h[1] = (f16)(acc[rr][1] + bb.y);
            p.h[2] = (f16)(acc[rr][2] + bb.z); p.h[3] = (f16)(acc[rr][3] + bb.w);
            ((ushort4*)t1)[(size_t)row * 32 + L] = p.u;
        }
    }
}

// ---------------- gemmB: hs2 = fp16(dis * (t1[n,128] @ W2[128,64])) ----------------
__global__ __launch_bounds__(256) void gemmB_k(const f16* __restrict__ t1, const float* __restrict__ W2,
                                               const float* __restrict__ dis, f16* __restrict__ hs2, int n) {
    __shared__ f16x2 sW[64 * 64];     // [kk][c] = (W2[2kk][c], W2[2kk+1][c])
    __shared__ f16x2 sA[64 * 66];     // [r][kk], padded (+2)
    int tid = threadIdx.x;
    for (int i = tid; i < 64 * 64; i += 256) {
        int kk = i >> 6, c = i & 63;
        f16x2 w; w[0] = (f16)W2[(2 * kk) * 64 + c]; w[1] = (f16)W2[(2 * kk + 1) * 64 + c];
        sW[i] = w;
    }
    int rowbase = blockIdx.x * 64;
    for (int i = tid; i < 2048; i += 256) {           // 64 rows x 32 ushort4
        int r = i >> 5, q = i & 31;
        int gr = rowbase + r;
        ushort4 u = make_ushort4(0, 0, 0, 0);
        if (gr < n) u = ((const ushort4*)t1)[(size_t)gr * 32 + q];
        ((ushort4*)sA)[r * 33 + q] = u;
    }
    __syncthreads();
    int L = tid & 15, rg = tid >> 4;                  // cols 4L..4L+3, rows rg*4..+3
    float acc[4][4] = {};
#pragma unroll 4
    for (int kk = 0; kk < 64; kk++) {
        f16x2 w0 = sW[kk * 64 + 4 * L];
        f16x2 w1 = sW[kk * 64 + 4 * L + 1];
        f16x2 w2 = sW[kk * 64 + 4 * L + 2];
        f16x2 w3 = sW[kk * 64 + 4 * L + 3];
#pragma unroll
        for (int rr = 0; rr < 4; rr++) {
            f16x2 a = sA[(rg * 4 + rr) * 66 + kk];
            acc[rr][0] = fdot2(a, w0, acc[rr][0]);
            acc[rr][1] = fdot2(a, w1, acc[rr][1]);
            acc[rr][2] = fdot2(a, w2, acc[rr][2]);
            acc[rr][3] = fdot2(a, w3, acc[rr][3]);
        }
    }
#pragma unroll
    for (int rr = 0; rr < 4; rr++) {
        int row = rowbase + rg * 4 + rr;
        if (row < n) {
            float d = dis[row];
            pk4 p;
            p.h[0] = (f16)(acc[rr][0] * d); p.h[1] = (f16)(acc[rr][1] * d);
            p.h[2] = (f16)(acc[rr][2] * d); p.h[3] = (f16)(acc[rr][3] * d);
            ((ushort4*)hs2)[(size_t)row * 16 + L] = p.u;
        }
    }
}

// ---------------- batchnorm: per-block partials, NO global atomics ----------------
__global__ __launch_bounds__(256) void bn_part_k(const f16* __restrict__ x, float* __restrict__ pbuf, int n) {
    __shared__ float4 ls[256], lq[256];
    int q = threadIdx.x & 15;     // cols 4q..4q+3
    int rg = threadIdx.x >> 4;    // 0..15
    float4 s = make_float4(0.f, 0.f, 0.f, 0.f);
    float4 ss = make_float4(0.f, 0.f, 0.f, 0.f);
    for (int row = blockIdx.x * 16 + rg; row < n; row += gridDim.x * 16) {
        pk4 p; p.u = ((const ushort4*)x)[(size_t)row * 16 + q];
        float v0 = p.h[0], v1 = p.h[1], v2 = p.h[2], v3 = p.h[3];
        s.x += v0; s.y += v1; s.z += v2; s.w += v3;
        ss.x += v0 * v0; ss.y += v1 * v1; ss.z += v2 * v2; ss.w += v3 * v3;
    }
    ls[threadIdx.x] = s; lq[threadIdx.x] = ss;
    __syncthreads();
    if (threadIdx.x < 16) {
        float4 S = make_float4(0.f, 0.f, 0.f, 0.f);
        float4 Q = make_float4(0.f, 0.f, 0.f, 0.f);
        for (int g = 0; g < 16; g++) {
            float4 a = ls[g * 16 + threadIdx.x], b = lq[g * 16 + threadIdx.x];
            S.x += a.x; S.y += a.y; S.z += a.z; S.w += a.w;
            Q.x += b.x; Q.y += b.y; Q.z += b.z; Q.w += b.w;
        }
        float4* dst = (float4*)(pbuf + (size_t)blockIdx.x * 128);
        dst[threadIdx.x] = S;
        dst[threadIdx.x + 16] = Q;
    }
}

__global__ __launch_bounds__(64) void bn_final_k(const float* __restrict__ pbuf,
                                                 const float* __restrict__ gamma, const float* __restrict__ beta,
                                                 int n, float* __restrict__ scale, float* __restrict__ shift) {
    int c = threadIdx.x;
    float s = 0.f, q = 0.f;
    for (int b = 0; b < BN_NB; b++) {
        s += pbuf[b * 128 + c];
        q += pbuf[b * 128 + 64 + c];
    }
    float inv_n = 1.f / (float)n;
    float mean = s * inv_n;
    float var = q * inv_n - mean * mean;          // biased variance
    float sc = gamma[c] * rsqrtf(var + EPS_BN);
    scale[c] = sc;
    shift[c] = beta[c] - mean * sc;
}

__global__ __launch_bounds__(256) void bn_apply_k(const f16* __restrict__ x, const float* __restrict__ scale,
                                                  const float* __restrict__ shift, float* __restrict__ out, int n) {
    __shared__ float sscale[64], sshift[64];
    if (threadIdx.x < 64) {
        sscale[threadIdx.x] = scale[threadIdx.x];
        sshift[threadIdx.x] = shift[threadIdx.x];
    }
    __syncthreads();
    int i = blockIdx.x * 256 + threadIdx.x;
    if (i < n * 16) {
        int c = (i & 15) * 4;
        pk4 p; p.u = ((const ushort4*)x)[i];
        float4 o;
        o.x = (float)p.h[0] * sscale[c]     + sshift[c];
        o.y = (float)p.h[1] * sscale[c + 1] + sshift[c + 1];
        o.z = (float)p.h[2] * sscale[c + 2] + sshift[c + 2];
        o.w = (float)p.h[3] * sscale[c + 3] + sshift[c + 3];
        ((float4*)out)[i] = o;
    }
}

extern "C" void kernel_launch(void* const* d_in, const int* in_sizes, int n_in,
                              void* d_out, int out_size, void* d_ws, size_t ws_size,
                              hipStream_t stream) {
    const float* emb   = (const float*)d_in[0];
    const float* W1    = (const float*)d_in[1];
    const float* b1    = (const float*)d_in[2];
    const float* W2    = (const float*)d_in[3];
    const float* b2    = (const float*)d_in[4];
    const float* gamma = (const float*)d_in[5];
    const float* beta  = (const float*)d_in[6];
    const int*   ei    = (const int*)d_in[7];     // [2,E] int32
    const int n = in_sizes[0] / 64;               // 100000
    const int E = in_sizes[7] / 2;                // 1600000
    const int* rowv = ei;                         // sources
    const int* colv = ei + E;                     // targets
    const int NBKT = (n + 127) / 128;             // 782

    char* ws = (char*)d_ws;
    size_t o = 0;
    auto alloc = [&](size_t bytes) -> char* {
        char* p = ws + o;
        o = (o + bytes + 255) & ~(size_t)255;
        return p;
    };
    int*   ghist   = (int*)alloc((size_t)SCAT_B * NBKT_PAD * 4);  // 1MB
    int*   bcnt    = (int*)alloc(NBKT_PAD * 4);
    int*   bstart  = (int*)alloc((NBKT_PAD + 1) * 4);
    int*   start   = (int*)alloc((size_t)(n + 1) * 4);
    float* dis     = (float*)alloc((size_t)n * 4);
    int*   srcs    = (int*)alloc((size_t)E * 4);
    float* pbuf    = (float*)alloc(BN_NB * 128 * 4);     // BN partials
    float* bnscale = (float*)alloc(256);
    float* bnshift = (float*)alloc(256);
    f16*   es      = (f16*)alloc((size_t)n * 64 * 2);    // dis*emb fp16
    f16*   ag1     = (f16*)alloc((size_t)n * 64 * 2);    // layer-1 aggregated
    f16*   t1      = (f16*)alloc((size_t)n * 128 * 2);   // h1 = ag1@W1+b1
    f16*   hs2     = (f16*)alloc((size_t)n * 64 * 2);    // dis*(t1@W2)
    f16*   h2      = (f16*)alloc((size_t)n * 64 * 2);    // pre-BN output
    unsigned* ebuf = (unsigned*)alloc((size_t)E * 4);    // packed bucket edges

    int epb = (E + SCAT_B - 1) / SCAT_B;          // 6250

    hist_k<<<SCAT_B, 1024, 0, stream>>>(colv, E, epb, ghist);
    scan_bucket_k<<<NBKT_PAD, 256, 0, stream>>>(ghist, bcnt);
    scan_total_k<<<1, 1024, 0, stream>>>(bcnt, bstart, start, n, E);
    scatB_k<<<SCAT_B, 1024, 0, stream>>>(rowv, colv, E, epb, ghist, bstart, ebuf);
    buildC_k<<<NBKT, 512, 0, stream>>>(ebuf, bstart, start, srcs, dis, n);

    prescale_k<<<(n * 16 + 255) / 256, 256, 0, stream>>>(emb, dis, es, n);
    agg64_k<<<(n + 15) / 16, 256, 0, stream>>>(es, start, srcs, dis, nullptr, ag1, n);
    gemmA_k<<<(n + 31) / 32, 256, 0, stream>>>(ag1, W1, b1, t1, n);
    gemmB_k<<<(n + 63) / 64, 256, 0, stream>>>(t1, W2, dis, hs2, n);
    agg64_k<<<(n + 15) / 16, 256, 0, stream>>>(hs2, start, srcs, dis, b2, h2, n);

    bn_part_k<<<BN_NB, 256, 0, stream>>>(h2, pbuf, n);
    bn_final_k<<<1, 64, 0, stream>>>(pbuf, gamma, beta, n, bnscale, bnshift);
    bn_apply_k<<<(n * 16 + 255) / 256, 256, 0, stream>>>(h2, bnscale, bnshift, (float*)d_out, n);
}